// Round 1
// baseline (191.237 us; speedup 1.0000x reference)
//
#include <hip/hip_runtime.h>
#include <cstdint>
#include <cstddef>

typedef __attribute__((ext_vector_type(8))) short bf16x8;
typedef __attribute__((ext_vector_type(4))) float f32x4;
typedef __attribute__((ext_vector_type(8))) unsigned short u16x8;

#define NB 8
#define NT 2048
#define ND 768
#define NC 2304     // 3*ND
#define NM (NB*NT)  // 16384
#define SPAN 128

__device__ __forceinline__ unsigned short f2bf(float f) {
    unsigned int u = __builtin_bit_cast(unsigned int, f);
    u += 0x7fffu + ((u >> 16) & 1u);   // RNE
    return (unsigned short)(u >> 16);
}

#define GLOAD16(G, L) __builtin_amdgcn_global_load_lds( \
    (const __attribute__((address_space(1))) unsigned int*)(G), \
    (__attribute__((address_space(3))) unsigned int*)(L), 16, 0, 0)

// ---------------- x (fp32) -> xb (bf16) ----------------
__global__ void k_conv_x(const float* __restrict__ x, unsigned short* __restrict__ xb) {
    int i = blockIdx.x * 256 + threadIdx.x;          // 8 elems per thread, exact grid
    const float4* p = (const float4*)x + (size_t)i * 2;
    float4 a = p[0], b = p[1];
    u16x8 v;
    v[0] = f2bf(a.x); v[1] = f2bf(a.y); v[2] = f2bf(a.z); v[3] = f2bf(a.w);
    v[4] = f2bf(b.x); v[5] = f2bf(b.y); v[6] = f2bf(b.z); v[7] = f2bf(b.w);
    *((u16x8*)xb + i) = v;
}

// ---------------- W [768][2304] fp32 -> wT [2304][768] bf16 ----------------
__global__ void k_conv_wT(const float* __restrict__ W, unsigned short* __restrict__ wT) {
    __shared__ unsigned short tile[64][72];
    const int k0 = blockIdx.x * 64, n0 = blockIdx.y * 64;
    const int tid = threadIdx.x;
    for (int e = 0; e < 16; ++e) {
        int idx = e * 256 + tid;
        int r = idx >> 6, c = idx & 63;              // r = k, c = n
        tile[r][c] = f2bf(W[(size_t)(k0 + r) * NC + n0 + c]);
    }
    __syncthreads();
    for (int e = 0; e < 16; ++e) {
        int idx = e * 256 + tid;
        int r = idx & 63, c = idx >> 6;              // r = k (fast, coalesced out), c = n
        wT[(size_t)(n0 + c) * ND + k0 + r] = tile[r][c];
    }
}

// ---------------- qkv = xb @ W + b : 128x128 tile, BK=64, XOR-swizzled LDS ----------------
__global__ void k_gemm(const unsigned short* __restrict__ xb,
                       const unsigned short* __restrict__ wT,
                       const float* __restrict__ bq,
                       unsigned short* __restrict__ qb,
                       unsigned short* __restrict__ kb,
                       unsigned short* __restrict__ vb) {
    __shared__ unsigned short Asw[128 * 64];
    __shared__ unsigned short Bsw[128 * 64];
    const int tid = threadIdx.x;
    const int lane = tid & 63, w = tid >> 6;
    const int m0 = blockIdx.x * 128, n0 = blockIdx.y * 128;
    const int wr = (w >> 1) * 64, wc = (w & 1) * 64;

    f32x4 acc[4][4];
    const f32x4 zf = {0.f, 0.f, 0.f, 0.f};
#pragma unroll
    for (int i = 0; i < 4; ++i)
#pragma unroll
        for (int j = 0; j < 4; ++j) acc[i][j] = zf;

    for (int kc = 0; kc < 12; ++kc) {
        if (kc) __syncthreads();
        // stage A/B tiles [128 rows][64 k] bf16, st-swizzle byte^((row&7)<<4)
        // via pre-swizzled global source + linear global_load_lds dest (m173 pattern)
#pragma unroll
        for (int t = 0; t < 4; ++t) {
            int chunk = w * 4 + t;                   // 16 x 1024B chunks
            int p = chunk * 1024 + lane * 16;
            int row = p >> 7;
            int col = (p & 127) ^ ((row & 7) << 4);  // byte col within 128B row
            GLOAD16(xb + (size_t)(m0 + row) * ND + kc * 64 + (col >> 1), Asw + chunk * 512);
            GLOAD16(wT + (size_t)(n0 + row) * ND + kc * 64 + (col >> 1), Bsw + chunk * 512);
        }
        __syncthreads();
#pragma unroll
        for (int kk = 0; kk < 2; ++kk) {
            bf16x8 af[4], bg[4];
#pragma unroll
            for (int i = 0; i < 4; ++i) {
                int r = wr + i * 16 + (lane & 15);
                af[i] = *(const bf16x8*)((const char*)Asw + r * 128 +
                        ((kk * 64 + (lane >> 4) * 16) ^ ((r & 7) << 4)));
                int c = wc + i * 16 + (lane & 15);
                bg[i] = *(const bf16x8*)((const char*)Bsw + c * 128 +
                        ((kk * 64 + (lane >> 4) * 16) ^ ((c & 7) << 4)));
            }
#pragma unroll
            for (int i = 0; i < 4; ++i)
#pragma unroll
                for (int j = 0; j < 4; ++j)
                    acc[i][j] = __builtin_amdgcn_mfma_f32_16x16x32_bf16(af[i], bg[j], acc[i][j], 0, 0, 0);
        }
    }

    // epilogue: +bias, bf16, split into q/k/v (each n-tile of 128 lies in one third)
    const int third = n0 / ND;
    unsigned short* ob = third == 0 ? qb : (third == 1 ? kb : vb);
    const int nl0 = n0 - third * ND + wc;
#pragma unroll
    for (int j = 0; j < 4; ++j) {
        int nl = nl0 + j * 16 + (lane & 15);
        float bias = bq[third * ND + nl];
#pragma unroll
        for (int i = 0; i < 4; ++i) {
#pragma unroll
            for (int r = 0; r < 4; ++r) {
                int m = m0 + wr + i * 16 + (lane >> 4) * 4 + r;  // C: col=lane&15, row=(lane>>4)*4+r
                ob[(size_t)m * ND + nl] = f2bf(acc[i][j][r] + bias);
            }
        }
    }
}

// ---------------- vb [B*T][D] -> vT [B][D][T] ----------------
__global__ void k_transpose_v(const unsigned short* __restrict__ vb, unsigned short* __restrict__ vT) {
    __shared__ unsigned short tile[64][72];
    const int t0 = blockIdx.x * 64, d0 = blockIdx.y * 64, b = blockIdx.z;
    const int tid = threadIdx.x;
#pragma unroll
    for (int e = 0; e < 2; ++e) {
        int vi = e * 256 + tid;
        int r = vi >> 3, c8 = vi & 7;                // r = t, c8*8 = d
        u16x8 v = *(const u16x8*)(vb + ((size_t)b * NT + t0 + r) * ND + d0 + c8 * 8);
        *(u16x8*)(&tile[r][c8 * 8]) = v;
    }
    __syncthreads();
#pragma unroll
    for (int e = 0; e < 2; ++e) {
        int vi = e * 256 + tid;
        int dr = vi >> 3, t8 = vi & 7;               // dr = d row, t8*8 = t
        u16x8 v;
#pragma unroll
        for (int q = 0; q < 8; ++q) v[q] = tile[t8 * 8 + q][dr];
        *(u16x8*)(vT + ((size_t)b * ND + d0 + dr) * NT + t0 + t8 * 8) = v;
    }
}

// ---------------- banded attention + LN. 1 block = (b, 64 q-rows), 4 waves ----------------
// LDS: S [64][200] | phase1 {Q [64][72], K [192][72]} aliased with phase2 V [64][200]
__global__ void k_attn(const unsigned short* __restrict__ qb,
                       const unsigned short* __restrict__ kb,
                       const unsigned short* __restrict__ vT,
                       const float* __restrict__ lnw,
                       const float* __restrict__ lnb,
                       float* __restrict__ out) {
    __shared__ char smem[62464];
    unsigned short* S  = (unsigned short*)smem;                    // [64][200]
    unsigned short* Qs = (unsigned short*)(smem + 25600);          // [64][72]
    unsigned short* Ks = (unsigned short*)(smem + 25600 + 9216);   // [192][72]
    unsigned short* Vs = (unsigned short*)(smem + 25600);          // [64][200] (aliases Qs/Ks)

    const int tid = threadIdx.x, lane = tid & 63, w = tid >> 6;
    const int q0 = blockIdx.x * 64;
    const int b  = blockIdx.y;
    const size_t rowQ = (size_t)b * NT + q0;

    f32x4 sacc[12];
    const f32x4 zf = {0.f, 0.f, 0.f, 0.f};
#pragma unroll
    for (int ct = 0; ct < 12; ++ct) sacc[ct] = zf;

    // ---- phase 1: S[64 x 192] = Q . K^T over D in 12 chunks of 64 ----
    for (int dc = 0; dc < 12; ++dc) {
        if (dc) __syncthreads();
#pragma unroll
        for (int e = 0; e < 2; ++e) {               // Q chunk [64][64]
            int vi = e * 256 + tid;
            int r = vi >> 3, c8 = vi & 7;
            u16x8 v = *(const u16x8*)(qb + (rowQ + r) * ND + dc * 64 + c8 * 8);
            *(u16x8*)(Qs + r * 72 + c8 * 8) = v;
        }
#pragma unroll
        for (int e = 0; e < 6; ++e) {               // K chunk [192][64], j = q0-128+r (clamped)
            int vi = e * 256 + tid;
            int r = vi >> 3, c8 = vi & 7;
            int j = q0 - 128 + r;
            int jc = j < 0 ? 0 : j;                  // garbage rows masked later
            u16x8 v = *(const u16x8*)(kb + ((size_t)b * NT + jc) * ND + dc * 64 + c8 * 8);
            *(u16x8*)(Ks + r * 72 + c8 * 8) = v;
        }
        __syncthreads();
#pragma unroll
        for (int kk = 0; kk < 2; ++kk) {
            bf16x8 aq = *(const bf16x8*)(Qs + (w * 16 + (lane & 15)) * 72 + kk * 32 + (lane >> 4) * 8);
#pragma unroll
            for (int ct = 0; ct < 12; ++ct) {
                bf16x8 bk = *(const bf16x8*)(Ks + (ct * 16 + (lane & 15)) * 72 + kk * 32 + (lane >> 4) * 8);
                sacc[ct] = __builtin_amdgcn_mfma_f32_16x16x32_bf16(aq, bk, sacc[ct], 0, 0, 0);
            }
        }
    }

    // ---- phase 1.5: mask + scale -> S (bf16) ----
    const float scl = 0.0031894436f;                 // 1/sqrt(768*128)
#pragma unroll
    for (int ct = 0; ct < 12; ++ct) {
        int jl = ct * 16 + (lane & 15);
        int j = q0 - 128 + jl;
#pragma unroll
        for (int r = 0; r < 4; ++r) {
            int il = w * 16 + (lane >> 4) * 4 + r;
            int i = q0 + il;
            int d = i - j;
            float v = (d >= 0 && d < SPAN && j >= 0) ? sacc[ct][r] * scl : 0.0f;
            S[il * 200 + jl] = f2bf(v);
        }
    }

    // ---- phase 2: out[64 x 768] = S @ V, 12 d-chunks; raw fp32 -> out, stats in regs ----
    float sum[4] = {0.f, 0.f, 0.f, 0.f}, ssq[4] = {0.f, 0.f, 0.f, 0.f};
    const size_t vbase = (size_t)b * ND * NT;

    for (int dc = 0; dc < 12; ++dc) {
        __syncthreads();                             // S ready / V region free
        {
            int r = tid >> 2;                        // V chunk: [64 d][192 j] from vT (j-fast!)
#pragma unroll
            for (int q = 0; q < 6; ++q) {
                int c8 = (tid & 3) + q * 4;          // 0..23
                int t = q0 - 128 + c8 * 8;
                int tc = t < 0 ? 0 : t;              // S==0 there -> garbage harmless
                u16x8 v = *(const u16x8*)(vT + vbase + (size_t)(dc * 64 + r) * NT + tc);
                *(u16x8*)(Vs + r * 200 + c8 * 8) = v;
            }
        }
        __syncthreads();
        f32x4 oacc[4];
#pragma unroll
        for (int dt = 0; dt < 4; ++dt) oacc[dt] = zf;
#pragma unroll
        for (int ks = 0; ks < 6; ++ks) {
            bf16x8 as = *(const bf16x8*)(S + (w * 16 + (lane & 15)) * 200 + ks * 32 + (lane >> 4) * 8);
#pragma unroll
            for (int dt = 0; dt < 4; ++dt) {
                bf16x8 bv = *(const bf16x8*)(Vs + (dt * 16 + (lane & 15)) * 200 + ks * 32 + (lane >> 4) * 8);
                oacc[dt] = __builtin_amdgcn_mfma_f32_16x16x32_bf16(as, bv, oacc[dt], 0, 0, 0);
            }
        }
#pragma unroll
        for (int dt = 0; dt < 4; ++dt) {
            int dcol = dc * 64 + dt * 16 + (lane & 15);
#pragma unroll
            for (int r = 0; r < 4; ++r) {
                int il = w * 16 + (lane >> 4) * 4 + r;
                float v = oacc[dt][r];
                sum[r] += v; ssq[r] += v * v;
                out[(rowQ + il) * ND + dcol] = v;    // raw, normalized below
            }
        }
    }

    // ---- LN: reduce stats across the 16 lanes sharing each row group ----
#pragma unroll
    for (int mx = 1; mx < 16; mx <<= 1) {
#pragma unroll
        for (int r = 0; r < 4; ++r) {
            sum[r] += __shfl_xor(sum[r], mx, 64);
            ssq[r] += __shfl_xor(ssq[r], mx, 64);
        }
    }

    __threadfence();                                 // drain raw stores + invalidate L1 (replay safety)

#pragma unroll
    for (int r = 0; r < 4; ++r) {
        int il = w * 16 + (lane >> 4) * 4 + r;
        float mu = sum[r] * (1.0f / 768.0f);
        float var = ssq[r] * (1.0f / 768.0f) - mu * mu;
        float rs = rsqrtf(var + 1e-5f);
        float* rowp = out + (rowQ + il) * ND;
#pragma unroll
        for (int t = 0; t < 12; ++t) {
            int c4 = t * 16 + (lane & 15);
            float4 v  = *(const float4*)(rowp + c4 * 4);
            float4 wv = *(const float4*)(lnw + c4 * 4);
            float4 bv = *(const float4*)(lnb + c4 * 4);
            float4 o;
            o.x = (v.x - mu) * rs * wv.x + bv.x;
            o.y = (v.y - mu) * rs * wv.y + bv.y;
            o.z = (v.z - mu) * rs * wv.z + bv.z;
            o.w = (v.w - mu) * rs * wv.w + bv.w;
            *(float4*)(rowp + c4 * 4) = o;
        }
    }
}

extern "C" void kernel_launch(void* const* d_in, const int* in_sizes, int n_in,
                              void* d_out, int out_size, void* d_ws, size_t ws_size,
                              hipStream_t stream) {
    const float* x   = (const float*)d_in[0];
    const float* W   = (const float*)d_in[1];
    const float* bqv = (const float*)d_in[2];
    const float* lnw = (const float*)d_in[3];
    const float* lnb = (const float*)d_in[4];
    float* out = (float*)d_out;

    char* ws = (char*)d_ws;
    const size_t SZ_XB = (size_t)NM * ND * 2;        // 25165824
    const size_t SZ_WT = (size_t)NC * ND * 2;        //  3538944
    const size_t SZ_P  = (size_t)NM * ND * 2;        // 25165824 each of q/k/v
    unsigned short* xb = (unsigned short*)ws;
    unsigned short* wT = (unsigned short*)(ws + SZ_XB);
    unsigned short* qb = (unsigned short*)(ws + SZ_XB + SZ_WT);
    unsigned short* kb = (unsigned short*)(ws + SZ_XB + SZ_WT + SZ_P);
    unsigned short* vb = (unsigned short*)(ws + SZ_XB + SZ_WT + 2 * SZ_P);
    unsigned short* vT = xb;                          // xb dead after GEMM; total ws use ~99.4 MB

    k_conv_x<<<dim3(NM * ND / (256 * 8)), dim3(256), 0, stream>>>(x, xb);
    k_conv_wT<<<dim3(ND / 64, NC / 64), dim3(256), 0, stream>>>(W, wT);
    k_gemm<<<dim3(NM / 128, NC / 128), dim3(256), 0, stream>>>(xb, wT, bqv, qb, kb, vb);
    k_transpose_v<<<dim3(NT / 64, ND / 64, NB), dim3(256), 0, stream>>>(vb, vT);
    k_attn<<<dim3(NT / 64, NB), dim3(256), 0, stream>>>(qb, kb, vT, lnw, lnb, out);
}

// Round 2
// 127.807 us; speedup vs baseline: 1.4963x; 1.4963x over previous
//
#include <hip/hip_runtime.h>
#include <cstdint>
#include <cstddef>

typedef __attribute__((ext_vector_type(8))) short bf16x8;
typedef __attribute__((ext_vector_type(4))) float f32x4;
typedef __attribute__((ext_vector_type(8))) unsigned short u16x8;

#define NB 8
#define NT 2048
#define ND 768
#define NC 2304     // 3*ND
#define NM (NB*NT)  // 16384
#define SPAN 128

__device__ __forceinline__ unsigned short f2bf(float f) {
    unsigned int u = __builtin_bit_cast(unsigned int, f);
    u += 0x7fffu + ((u >> 16) & 1u);   // RNE
    return (unsigned short)(u >> 16);
}

#define GLOAD16(G, L) __builtin_amdgcn_global_load_lds( \
    (const __attribute__((address_space(1))) unsigned int*)(G), \
    (__attribute__((address_space(3))) unsigned int*)(L), 16, 0, 0)

// ---------------- x (fp32) -> xb (bf16) ----------------
__global__ void k_conv_x(const float* __restrict__ x, unsigned short* __restrict__ xb) {
    int i = blockIdx.x * 256 + threadIdx.x;          // 8 elems per thread, exact grid
    const float4* p = (const float4*)x + (size_t)i * 2;
    float4 a = p[0], b = p[1];
    u16x8 v;
    v[0] = f2bf(a.x); v[1] = f2bf(a.y); v[2] = f2bf(a.z); v[3] = f2bf(a.w);
    v[4] = f2bf(b.x); v[5] = f2bf(b.y); v[6] = f2bf(b.z); v[7] = f2bf(b.w);
    *((u16x8*)xb + i) = v;
}

// ---------------- W [768][2304] fp32 -> wT [2304][768] bf16 ----------------
__global__ void k_conv_wT(const float* __restrict__ W, unsigned short* __restrict__ wT) {
    __shared__ unsigned short tile[64][72];
    const int k0 = blockIdx.x * 64, n0 = blockIdx.y * 64;
    const int tid = threadIdx.x;
    for (int e = 0; e < 16; ++e) {
        int idx = e * 256 + tid;
        int r = idx >> 6, c = idx & 63;              // r = k, c = n
        tile[r][c] = f2bf(W[(size_t)(k0 + r) * NC + n0 + c]);
    }
    __syncthreads();
    for (int e = 0; e < 16; ++e) {
        int idx = e * 256 + tid;
        int r = idx & 63, c = idx >> 6;              // r = k (fast, coalesced out), c = n
        wT[(size_t)(n0 + c) * ND + k0 + r] = tile[r][c];
    }
}

// ---------------- qkv = xb @ W + b : 128x128 tile, BK=64, XOR-swizzled LDS ----------------
__global__ void k_gemm(const unsigned short* __restrict__ xb,
                       const unsigned short* __restrict__ wT,
                       const float* __restrict__ bq,
                       unsigned short* __restrict__ qb,
                       unsigned short* __restrict__ kb,
                       unsigned short* __restrict__ vb) {
    __shared__ unsigned short Asw[128 * 64];
    __shared__ unsigned short Bsw[128 * 64];
    const int tid = threadIdx.x;
    const int lane = tid & 63, w = tid >> 6;
    const int m0 = blockIdx.x * 128, n0 = blockIdx.y * 128;
    const int wr = (w >> 1) * 64, wc = (w & 1) * 64;

    f32x4 acc[4][4];
    const f32x4 zf = {0.f, 0.f, 0.f, 0.f};
#pragma unroll
    for (int i = 0; i < 4; ++i)
#pragma unroll
        for (int j = 0; j < 4; ++j) acc[i][j] = zf;

    for (int kc = 0; kc < 12; ++kc) {
        if (kc) __syncthreads();
#pragma unroll
        for (int t = 0; t < 4; ++t) {
            int chunk = w * 4 + t;                   // 16 x 1024B chunks
            int p = chunk * 1024 + lane * 16;
            int row = p >> 7;
            int col = (p & 127) ^ ((row & 7) << 4);  // byte col within 128B row
            GLOAD16(xb + (size_t)(m0 + row) * ND + kc * 64 + (col >> 1), Asw + chunk * 512);
            GLOAD16(wT + (size_t)(n0 + row) * ND + kc * 64 + (col >> 1), Bsw + chunk * 512);
        }
        __syncthreads();
#pragma unroll
        for (int kk = 0; kk < 2; ++kk) {
            bf16x8 af[4], bg[4];
#pragma unroll
            for (int i = 0; i < 4; ++i) {
                int r = wr + i * 16 + (lane & 15);
                af[i] = *(const bf16x8*)((const char*)Asw + r * 128 +
                        ((kk * 64 + (lane >> 4) * 16) ^ ((r & 7) << 4)));
                int c = wc + i * 16 + (lane & 15);
                bg[i] = *(const bf16x8*)((const char*)Bsw + c * 128 +
                        ((kk * 64 + (lane >> 4) * 16) ^ ((c & 7) << 4)));
            }
#pragma unroll
            for (int i = 0; i < 4; ++i)
#pragma unroll
                for (int j = 0; j < 4; ++j)
                    acc[i][j] = __builtin_amdgcn_mfma_f32_16x16x32_bf16(af[i], bg[j], acc[i][j], 0, 0, 0);
        }
    }

    const int third = n0 / ND;
    unsigned short* ob = third == 0 ? qb : (third == 1 ? kb : vb);
    const int nl0 = n0 - third * ND + wc;
#pragma unroll
    for (int j = 0; j < 4; ++j) {
        int nl = nl0 + j * 16 + (lane & 15);
        float bias = bq[third * ND + nl];
#pragma unroll
        for (int i = 0; i < 4; ++i) {
#pragma unroll
            for (int r = 0; r < 4; ++r) {
                int m = m0 + wr + i * 16 + (lane >> 4) * 4 + r;  // C: col=lane&15, row=(lane>>4)*4+r
                ob[(size_t)m * ND + nl] = f2bf(acc[i][j][r] + bias);
            }
        }
    }
}

// ---------------- vb [B*T][D] -> vT [B][D][T] ----------------
__global__ void k_transpose_v(const unsigned short* __restrict__ vb, unsigned short* __restrict__ vT) {
    __shared__ unsigned short tile[64][72];
    const int t0 = blockIdx.x * 64, d0 = blockIdx.y * 64, b = blockIdx.z;
    const int tid = threadIdx.x;
#pragma unroll
    for (int e = 0; e < 2; ++e) {
        int vi = e * 256 + tid;
        int r = vi >> 3, c8 = vi & 7;                // r = t, c8*8 = d
        u16x8 v = *(const u16x8*)(vb + ((size_t)b * NT + t0 + r) * ND + d0 + c8 * 8);
        *(u16x8*)(&tile[r][c8 * 8]) = v;
    }
    __syncthreads();
#pragma unroll
    for (int e = 0; e < 2; ++e) {
        int vi = e * 256 + tid;
        int dr = vi >> 3, t8 = vi & 7;               // dr = d row, t8*8 = t
        u16x8 v;
#pragma unroll
        for (int q = 0; q < 8; ++q) v[q] = tile[t8 * 8 + q][dr];
        *(u16x8*)(vT + ((size_t)b * ND + d0 + dr) * NT + t0 + t8 * 8) = v;
    }
}

// ---------------- banded attention + fused LN, 16 waves, reg-resident out ----------------
// LDS map: S [64][200] u16 @0 (25600B) | R=25600: phase1 QK dbuf 2x32KB ([64][64]Q + [192][64]K,
// XOR-swizzled rows) | phase2 V dbuf 2x48KB ([768 d][32 j] swizzled) aliases QK | LN scratch @R.
__global__ __launch_bounds__(1024) void k_attn(const unsigned short* __restrict__ qb,
                       const unsigned short* __restrict__ kb,
                       const unsigned short* __restrict__ vT,
                       const float* __restrict__ lnw,
                       const float* __restrict__ lnb,
                       float* __restrict__ out) {
    __shared__ char smem[123904];
    unsigned short* S = (unsigned short*)smem;       // [64][200]
    char* R = smem + 25600;

    const int tid = threadIdx.x, lane = tid & 63, w = tid >> 6;
    // XCD-contiguous swizzle: 256 blocks = 8 XCD x 32; one batch per XCD (K/V stays in its L2)
    const int bid = blockIdx.x;
    const int nid = (bid & 7) * 32 + (bid >> 3);
    const int b = nid >> 5;
    const int q0 = (nid & 31) * 64;
    const size_t rowQ = (size_t)b * NT + q0;
    const size_t rowK = (size_t)b * NT;
    const size_t vbase = (size_t)b * ND * NT;

    // ---- phase 1: S[64x192] = Q.K^T, 12 d-chunks of 64, min-2-phase dbuf ----
    f32x4 sacc[3];
    const f32x4 zf = {0.f, 0.f, 0.f, 0.f};
#pragma unroll
    for (int s = 0; s < 3; ++s) sacc[s] = zf;

    const int qrow = (w >> 2) * 16 + (lane & 15);
    const int kct = (w & 3) * 3;

    // stage QK for d-chunk dc into buffer cur (2048 x 16B loads, 2/thread)
    auto stage_qk = [&](int dc, int cur) {
        char* L = R + cur * 32768;
#pragma unroll
        for (int e = 0; e < 2; ++e) {
            int s = w * 128 + e * 64 + lane;         // wave-uniform base + lane (rule #21)
            const unsigned short* src;
            if (s < 512) {                            // Q: row r, 8 slots of 16B, XOR (r&7)
                int r = s >> 3, sl = s & 7;
                src = qb + (rowQ + r) * ND + dc * 64 + 8 * (sl ^ (r & 7));
            } else {                                  // K: 192 rows, window j = q0-128+r
                int t = s - 512;
                int r = t >> 3, sl = t & 7;
                int j = q0 - 128 + r; if (j < 0) j = 0;   // masked via S=0 later
                src = kb + (rowK + j) * ND + dc * 64 + 8 * (sl ^ (r & 7));
            }
            GLOAD16(src, L + (w * 128 + e * 64) * 16);
        }
    };

    stage_qk(0, 0);
    __syncthreads();
    for (int dc = 0; dc < 12; ++dc) {
        int cur = dc & 1;
        if (dc < 11) stage_qk(dc + 1, cur ^ 1);      // next-tile loads fly under compute
        const char* Lq = R + cur * 32768;
        const char* Lk = Lq + 8192;
#pragma unroll
        for (int kk = 0; kk < 2; ++kk) {
            int bq_ = (((lane >> 4) * 16 + kk * 64)) ^ ((qrow & 7) << 4);
            bf16x8 aq = *(const bf16x8*)(Lq + qrow * 128 + bq_);
#pragma unroll
            for (int s = 0; s < 3; ++s) {
                int krow = (kct + s) * 16 + (lane & 15);
                int bk_ = (((lane >> 4) * 16 + kk * 64)) ^ ((krow & 7) << 4);
                bf16x8 bk = *(const bf16x8*)(Lk + krow * 128 + bk_);
                sacc[s] = __builtin_amdgcn_mfma_f32_16x16x32_bf16(aq, bk, sacc[s], 0, 0, 0);
            }
        }
        __syncthreads();
    }

    // ---- phase 1.5: mask + scale -> S bf16 ----
    const float scl = 0.0031894436f;                 // 1/sqrt(768*128)
#pragma unroll
    for (int s = 0; s < 3; ++s) {
        int jl = (kct + s) * 16 + (lane & 15);
        int j = q0 - 128 + jl;
#pragma unroll
        for (int e = 0; e < 4; ++e) {
            int il = (w >> 2) * 16 + (lane >> 4) * 4 + e;
            int d = (q0 + il) - j;
            float v = (d >= 0 && d < SPAN && j >= 0) ? sacc[s][e] * scl : 0.0f;
            S[il * 200 + jl] = f2bf(v);
        }
    }

    // ---- phase 2: out[64x768] = S @ V, reg-resident acc, 6 j-chunks of 32, dbuf ----
    // wave w: all 4 row-tiles x col-tiles {w*3..w*3+2} (48 VGPR acc)
    auto stage_v = [&](int c, int cur) {
        char* L = R + cur * 49152;
        int j0 = q0 - 128 + c * 32;
#pragma unroll
        for (int e = 0; e < 3; ++e) {
            int s = w * 192 + e * 64 + lane;
            int d = s >> 2, sl = s & 3;              // [768 d][4 x 16B], XOR (d&3)
            int j = j0 + 8 * (sl ^ (d & 3)); if (j < 0) j = 0;
            GLOAD16(vT + vbase + (size_t)d * NT + j, L + (w * 192 + e * 64) * 16);
        }
    };

    f32x4 acc[4][3];
#pragma unroll
    for (int rt = 0; rt < 4; ++rt)
#pragma unroll
        for (int ct = 0; ct < 3; ++ct) acc[rt][ct] = zf;

    stage_v(0, 0);                                   // overlaps with other waves' S writes
    __syncthreads();
    for (int c = 0; c < 6; ++c) {
        int cur = c & 1;
        if (c < 5) stage_v(c + 1, cur ^ 1);
        const char* Lv = R + cur * 49152;
        bf16x8 as[4], bv[3];
#pragma unroll
        for (int rt = 0; rt < 4; ++rt)
            as[rt] = *(const bf16x8*)((const char*)S + (rt * 16 + (lane & 15)) * 400 + c * 64 + (lane >> 4) * 16);
#pragma unroll
        for (int ct = 0; ct < 3; ++ct) {
            int d = (w * 3 + ct) * 16 + (lane & 15);
            bv[ct] = *(const bf16x8*)(Lv + d * 64 + (((lane >> 4) * 16) ^ ((d & 3) << 4)));
        }
#pragma unroll
        for (int rt = 0; rt < 4; ++rt)
#pragma unroll
            for (int ct = 0; ct < 3; ++ct)
                acc[rt][ct] = __builtin_amdgcn_mfma_f32_16x16x32_bf16(as[rt], bv[ct], acc[rt][ct], 0, 0, 0);
        __syncthreads();
    }

    // ---- fused LN: per-lane partials -> shfl over 16 col-lanes -> LDS cross-wave ----
    float psum[4][4], pssq[4][4];                    // [rt][e]
#pragma unroll
    for (int rt = 0; rt < 4; ++rt)
#pragma unroll
        for (int e = 0; e < 4; ++e) {
            float s = 0.f, q = 0.f;
#pragma unroll
            for (int ct = 0; ct < 3; ++ct) { float v = acc[rt][ct][e]; s += v; q += v * v; }
            psum[rt][e] = s; pssq[rt][e] = q;
        }
#pragma unroll
    for (int mx = 1; mx < 16; mx <<= 1)
#pragma unroll
        for (int rt = 0; rt < 4; ++rt)
#pragma unroll
            for (int e = 0; e < 4; ++e) {
                psum[rt][e] += __shfl_xor(psum[rt][e], mx, 64);
                pssq[rt][e] += __shfl_xor(pssq[rt][e], mx, 64);
            }

    float* P = (float*)R;                            // [64 rows][16 waves][2], QK/V region dead
    float* F = (float*)(R + 8192);                   // [64 rows][2] -> (mu, rs)
    if ((lane & 15) == 0) {
#pragma unroll
        for (int rt = 0; rt < 4; ++rt)
#pragma unroll
            for (int e = 0; e < 4; ++e) {
                int r = rt * 16 + (lane >> 4) * 4 + e;
                P[(r * 16 + w) * 2] = psum[rt][e];
                P[(r * 16 + w) * 2 + 1] = pssq[rt][e];
            }
    }
    __syncthreads();
    if (tid < 64) {
        float s = 0.f, q = 0.f;
#pragma unroll
        for (int ww = 0; ww < 16; ++ww) { s += P[(tid * 16 + ww) * 2]; q += P[(tid * 16 + ww) * 2 + 1]; }
        float mu = s * (1.0f / 768.0f);
        float var = q * (1.0f / 768.0f) - mu * mu;
        F[tid * 2] = mu;
        F[tid * 2 + 1] = rsqrtf(var + 1e-5f);
    }
    __syncthreads();

    // ---- normalize + single write ----
    float lw[3], lb_[3];
#pragma unroll
    for (int ct = 0; ct < 3; ++ct) {
        int dcol = (w * 3 + ct) * 16 + (lane & 15);
        lw[ct] = lnw[dcol]; lb_[ct] = lnb[dcol];
    }
#pragma unroll
    for (int rt = 0; rt < 4; ++rt)
#pragma unroll
        for (int e = 0; e < 4; ++e) {
            int row = rt * 16 + (lane >> 4) * 4 + e;
            float mu = F[row * 2], rs = F[row * 2 + 1];
            float* rowp = out + (rowQ + row) * ND;
#pragma unroll
            for (int ct = 0; ct < 3; ++ct) {
                int dcol = (w * 3 + ct) * 16 + (lane & 15);
                rowp[dcol] = (acc[rt][ct][e] - mu) * rs * lw[ct] + lb_[ct];
            }
        }
}

extern "C" void kernel_launch(void* const* d_in, const int* in_sizes, int n_in,
                              void* d_out, int out_size, void* d_ws, size_t ws_size,
                              hipStream_t stream) {
    const float* x   = (const float*)d_in[0];
    const float* W   = (const float*)d_in[1];
    const float* bqv = (const float*)d_in[2];
    const float* lnw = (const float*)d_in[3];
    const float* lnb = (const float*)d_in[4];
    float* out = (float*)d_out;

    char* ws = (char*)d_ws;
    const size_t SZ_XB = (size_t)NM * ND * 2;
    const size_t SZ_WT = (size_t)NC * ND * 2;
    const size_t SZ_P  = (size_t)NM * ND * 2;
    unsigned short* xb = (unsigned short*)ws;
    unsigned short* wT = (unsigned short*)(ws + SZ_XB);
    unsigned short* qb = (unsigned short*)(ws + SZ_XB + SZ_WT);
    unsigned short* kb = (unsigned short*)(ws + SZ_XB + SZ_WT + SZ_P);
    unsigned short* vb = (unsigned short*)(ws + SZ_XB + SZ_WT + 2 * SZ_P);
    unsigned short* vT = xb;                          // xb dead after GEMM

    k_conv_x<<<dim3(NM * ND / (256 * 8)), dim3(256), 0, stream>>>(x, xb);
    k_conv_wT<<<dim3(ND / 64, NC / 64), dim3(256), 0, stream>>>(W, wT);
    k_gemm<<<dim3(NM / 128, NC / 128), dim3(256), 0, stream>>>(xb, wT, bqv, qb, kb, vb);
    k_transpose_v<<<dim3(NT / 64, ND / 64, NB), dim3(256), 0, stream>>>(vb, vT);
    k_attn<<<dim3(256), dim3(1024), 0, stream>>>(qb, kb, vT, lnw, lnb, out);
}